// Round 5
// baseline (224.266 us; speedup 1.0000x reference)
//
#include <hip/hip_runtime.h>
#include <stdint.h>

// QJL estimator: est[row] = DEQ * sum_m sign(key_row . S_m) * (query_row . S_m)
//   qjl_prep : emit S as bf16 hi/lo pair in MFMA *fragment order*:
//              ST[s][h][t][c][lane][j]  -> every S-frag load in qjl_main is
//              base + lane*16B, one coalesced 1KB instruction.
//   qjl_main : per-wave 32 rows x 256 m, TWO PASSES over m-slices:
//              pass1 (k): kproj = kh*Sh + kl*Sh + kh*Sl -> pack sign bits,
//                         borderline |kproj|<DELTA -> per-block worklist.
//              pass2 (q): qproj = qh*Sh -> part += sign*qproj.
//              Passes keep peak VGPR ~116 (R4's fused version spilled ~22MB).
//   qjl_fix  : per-block segments, fp64 recompute of borderline dots, atomic fix.
//
// MFMA layout (validated empirically R1-R4, gfx950 mfma_f32_16x16x32_bf16):
//   operands: lane l holds X[idx = l&15][k = (l>>4)*8 + j], j=0..7
//   D: arg0's idx -> D-row = (l>>4)*4 + r ; arg1's idx -> D-col = l&15

typedef __attribute__((ext_vector_type(8))) short bf16x8;
typedef __attribute__((ext_vector_type(4))) float f32x4;

#define DEQUANT 0.004895758348888673f  // sqrt(pi/2)/256
#define DELTA 0.01f
#define SEG 512  // worklist capacity per block (expected ~23/block)

static __device__ __forceinline__ unsigned short f2bf(float f) {
  union { float f; uint32_t u; } v; v.f = f;
  return (unsigned short)((v.u + 0x7FFFu + ((v.u >> 16) & 1u)) >> 16);  // RNE
}
static __device__ __forceinline__ float bf2f(unsigned short h) {
  union { uint32_t u; float f; } v; v.u = ((uint32_t)h) << 16;
  return v.f;
}

// ST element count = 4(s) * 2(h) * 4(t) * 4(c) * 64(lane) * 8(j) = 65536 shorts
__global__ void qjl_prep(const float* __restrict__ S, unsigned short* __restrict__ ST) {
  int i = blockIdx.x * blockDim.x + threadIdx.x;  // grid covers 65536
  const int j = i & 7;
  const int l = (i >> 3) & 63;
  const int c = (i >> 9) & 3;
  const int t = (i >> 11) & 3;
  const int h = (i >> 13) & 1;
  const int s = i >> 14;
  const int m = s * 64 + t * 16 + (l & 15);
  const int k = c * 32 + (l >> 4) * 8 + j;
  const float f = S[m * 128 + k];
  const unsigned short hi = f2bf(f);
  ST[i] = h ? f2bf(f - bf2f(hi)) : hi;
}

__global__ __launch_bounds__(256, 3) void qjl_main(
    const float* __restrict__ Q, const float* __restrict__ K,
    const unsigned short* __restrict__ ST,
    float* __restrict__ out, unsigned int* __restrict__ blockCount,
    unsigned int* __restrict__ wl) {
  __shared__ unsigned int l_cnt;
  __shared__ unsigned int l_ent[SEG];

  const int wave = threadIdx.x >> 6;
  const int lane = threadIdx.x & 63;
  const int col  = lane & 15;   // data-row within 16-row tile (D col)
  const int kg   = lane >> 4;   // k-group for operand frags
  const int rowbase = (blockIdx.x * 4 + wave) * 32;  // 32 rows per wave

  if (threadIdx.x == 0) l_cnt = 0u;
  __syncthreads();

  // sign masks: bit (s&1)*16 + t*4 + r of smask[a][s>>1]
  unsigned int smask[2][2] = {{0u, 0u}, {0u, 0u}};

  // ================= PASS 1: key projections -> sign bits =================
  {
    bf16x8 khB[2][4], klB[2][4];
#pragma unroll
    for (int a = 0; a < 2; ++a) {
      const float* krow = K + (size_t)(rowbase + a * 16 + col) * 128 + kg * 8;
#pragma unroll
      for (int c = 0; c < 4; ++c) {
        float kf[8];
        *(float4*)(&kf[0]) = *(const float4*)(krow + c * 32);
        *(float4*)(&kf[4]) = *(const float4*)(krow + c * 32 + 4);
#pragma unroll
        for (int j = 0; j < 8; ++j) {
          unsigned short h = f2bf(kf[j]);
          khB[a][c][j] = (short)h;
          klB[a][c][j] = (short)f2bf(kf[j] - bf2f(h));
        }
      }
    }

#pragma unroll
    for (int s = 0; s < 4; ++s) {
      f32x4 acck[2][4];
#pragma unroll
      for (int a = 0; a < 2; ++a)
#pragma unroll
        for (int t = 0; t < 4; ++t) acck[a][t] = (f32x4){0.f, 0.f, 0.f, 0.f};
#pragma unroll
      for (int t = 0; t < 4; ++t) {
#pragma unroll
        for (int c = 0; c < 4; ++c) {
          const bf16x8 bh = *(const bf16x8*)(ST + (size_t)(((s * 2 + 0) * 4 + t) * 4 + c) * 512 + lane * 8);
          const bf16x8 bl = *(const bf16x8*)(ST + (size_t)(((s * 2 + 1) * 4 + t) * 4 + c) * 512 + lane * 8);
#pragma unroll
          for (int a = 0; a < 2; ++a) {
            acck[a][t] = __builtin_amdgcn_mfma_f32_16x16x32_bf16(bh, khB[a][c], acck[a][t], 0, 0, 0);
            acck[a][t] = __builtin_amdgcn_mfma_f32_16x16x32_bf16(bh, klB[a][c], acck[a][t], 0, 0, 0);
            acck[a][t] = __builtin_amdgcn_mfma_f32_16x16x32_bf16(bl, khB[a][c], acck[a][t], 0, 0, 0);
          }
        }
      }
      // epilogue: pack signs, push borderline entries
#pragma unroll
      for (int a = 0; a < 2; ++a)
#pragma unroll
        for (int t = 0; t < 4; ++t)
#pragma unroll
          for (int r = 0; r < 4; ++r) {
            const float kp = acck[a][t][r];
            if (kp > 0.f) smask[a][s >> 1] |= (1u << ((s & 1) * 16 + t * 4 + r));
            if (__builtin_fabsf(kp) < DELTA) {
              const int m = s * 64 + t * 16 + kg * 4 + r;
              const int row = rowbase + a * 16 + col;
              const unsigned int code = (kp > 0.f) ? 1u : 2u;  // matches applied sign
              const unsigned int idx = atomicAdd(&l_cnt, 1u);
              if (idx < SEG) l_ent[idx] = (code << 25) | ((unsigned int)row << 8) | (unsigned int)m;
            }
          }
    }
  }

  // ================= PASS 2: query projections -> estimator =================
  float part[2] = {0.f, 0.f};
  {
    bf16x8 qB[2][4];
#pragma unroll
    for (int a = 0; a < 2; ++a) {
      const float* qrow = Q + (size_t)(rowbase + a * 16 + col) * 128 + kg * 8;
#pragma unroll
      for (int c = 0; c < 4; ++c) {
        float qf[8];
        *(float4*)(&qf[0]) = *(const float4*)(qrow + c * 32);
        *(float4*)(&qf[4]) = *(const float4*)(qrow + c * 32 + 4);
#pragma unroll
        for (int j = 0; j < 8; ++j) qB[a][c][j] = (short)f2bf(qf[j]);
      }
    }

#pragma unroll
    for (int s = 0; s < 4; ++s) {
      f32x4 accq[2][4];
#pragma unroll
      for (int a = 0; a < 2; ++a)
#pragma unroll
        for (int t = 0; t < 4; ++t) accq[a][t] = (f32x4){0.f, 0.f, 0.f, 0.f};
#pragma unroll
      for (int t = 0; t < 4; ++t) {
#pragma unroll
        for (int c = 0; c < 4; ++c) {
          const bf16x8 bh = *(const bf16x8*)(ST + (size_t)(((s * 2 + 0) * 4 + t) * 4 + c) * 512 + lane * 8);
#pragma unroll
          for (int a = 0; a < 2; ++a)
            accq[a][t] = __builtin_amdgcn_mfma_f32_16x16x32_bf16(bh, qB[a][c], accq[a][t], 0, 0, 0);
        }
      }
#pragma unroll
      for (int a = 0; a < 2; ++a)
#pragma unroll
        for (int t = 0; t < 4; ++t)
#pragma unroll
          for (int r = 0; r < 4; ++r) {
            const unsigned int bit = (smask[a][s >> 1] >> ((s & 1) * 16 + t * 4 + r)) & 1u;
            part[a] += bit ? accq[a][t][r] : -accq[a][t][r];
          }
    }
  }

  // reduce the 4 k-groups holding the same data-row (xor lane bits 4,5)
#pragma unroll
  for (int a = 0; a < 2; ++a) {
    float v = part[a];
    v += __shfl_xor(v, 16);
    v += __shfl_xor(v, 32);
    if (lane < 16) out[rowbase + a * 16 + lane] = v * DEQUANT;
  }

  // flush per-block worklist segment
  __syncthreads();
  unsigned int n = l_cnt;
  if (n > SEG) n = SEG;
  if (threadIdx.x == 0) blockCount[blockIdx.x] = n;
  for (unsigned int i = threadIdx.x; i < n; i += 256)
    wl[(size_t)blockIdx.x * SEG + i] = l_ent[i];
}

__global__ __launch_bounds__(256) void qjl_fix(
    const float* __restrict__ Q, const float* __restrict__ K, const float* __restrict__ S,
    float* __restrict__ out, const unsigned int* __restrict__ blockCount,
    const unsigned int* __restrict__ wl) {
  const unsigned int n = blockCount[blockIdx.x];
  const int lane = threadIdx.x & 63;
  const int wave = threadIdx.x >> 6;
  for (unsigned int e = wave; e < n; e += 4) {
    const unsigned int ent = wl[(size_t)blockIdx.x * SEG + e];
    const unsigned int m = ent & 255u;
    const unsigned int row = (ent >> 8) & 0x1FFFFu;
    const unsigned int code = ent >> 25;
    const float s_old = (code == 1u) ? 1.f : -1.f;
    const float* kr = K + (size_t)row * 128;
    const float* qr = Q + (size_t)row * 128;
    const float* sr = S + (size_t)m * 128;
    const int d = lane * 2;
    double kp = (double)kr[d] * (double)sr[d] + (double)kr[d + 1] * (double)sr[d + 1];
    double qp = (double)qr[d] * (double)sr[d] + (double)qr[d + 1] * (double)sr[d + 1];
#pragma unroll
    for (int mask = 1; mask < 64; mask <<= 1) {
      kp += __shfl_xor(kp, mask);
      qp += __shfl_xor(qp, mask);
    }
    if (lane == 0) {
      const float s_new = (kp > 0.0) ? 1.f : ((kp < 0.0) ? -1.f : 0.f);
      const float dlt = (s_new - s_old) * (float)qp * DEQUANT;
      if (dlt != 0.f) atomicAdd(out + row, dlt);
    }
  }
}

extern "C" void kernel_launch(void* const* d_in, const int* in_sizes, int n_in,
                              void* d_out, int out_size, void* d_ws, size_t ws_size,
                              hipStream_t stream) {
  const float* Q = (const float*)d_in[0];
  const float* K = (const float*)d_in[1];
  const float* S = (const float*)d_in[2];
  float* out = (float*)d_out;
  const int rows = in_sizes[0] / 128;  // 4*32768 = 131072
  const int sn = in_sizes[2];          // 256*128 = 32768
  const int nblk = rows / 128;         // 1024 blocks, 128 rows each

  // workspace: [ST bf16 2*sn][blockCount u32 nblk][wl u32 nblk*SEG]
  unsigned short* ST = (unsigned short*)d_ws;
  unsigned int* blockCount = (unsigned int*)((char*)d_ws + (size_t)sn * 4);
  unsigned int* wl = blockCount + nblk;

  hipLaunchKernelGGL(qjl_prep, dim3((2 * sn) / 256), dim3(256), 0, stream, S, ST);
  hipLaunchKernelGGL(qjl_main, dim3(nblk), dim3(256), 0, stream,
                     Q, K, ST, out, blockCount, wl);
  hipLaunchKernelGGL(qjl_fix, dim3(nblk), dim3(256), 0, stream,
                     Q, K, S, out, blockCount, wl);
}

// Round 6
// 185.299 us; speedup vs baseline: 1.2103x; 1.2103x over previous
//
#include <hip/hip_runtime.h>
#include <stdint.h>

// QJL estimator: est[row] = DEQ * sum_m sign(key_row . S_m) * (query_row . S_m)
//   qjl_prep : emit S as bf16 hi/lo pair in MFMA *fragment order*:
//              ST[s][h][t][c][lane][j] -> fragment load = base + lane*16B.
//   qjl_main : 1024-thread block (16 waves), 512 rows/block, grid 256 (1/CU).
//              Stage ALL of ST (128 KB) into LDS once; both passes read
//              fragments via ds_read_b128 (R5 had every wave re-streaming
//              192 KB of ST through a thrashed 32 KB L1 -> latency-bound).
//              pass1 (k): kproj = kh*Sh + kl*Sh + kh*Sl -> packed sign bits,
//                         |kproj|<DELTA -> per-block worklist (LDS atomics).
//              pass2 (q): qproj = qh*Sh -> part += sign*qproj.
//   qjl_fix  : per-block segments, fp64 recompute of borderline dots, atomic fix.
//
// MFMA layout (validated empirically R1-R5, gfx950 mfma_f32_16x16x32_bf16):
//   operands: lane l holds X[idx = l&15][k = (l>>4)*8 + j], j=0..7
//   D: arg0's idx -> D-row = (l>>4)*4 + r ; arg1's idx -> D-col = l&15

typedef __attribute__((ext_vector_type(8))) short bf16x8;
typedef __attribute__((ext_vector_type(4))) float f32x4;

#define DEQUANT 0.004895758348888673f  // sqrt(pi/2)/256
#define DELTA 0.01f
#define SEG 512        // worklist capacity per block (expected ~92, Poisson)
#define ST_SHORTS 65536  // 4s*2h*4t*4c*64lane*8j

static __device__ __forceinline__ unsigned short f2bf(float f) {
  union { float f; uint32_t u; } v; v.f = f;
  return (unsigned short)((v.u + 0x7FFFu + ((v.u >> 16) & 1u)) >> 16);  // RNE
}
static __device__ __forceinline__ float bf2f(unsigned short h) {
  union { uint32_t u; float f; } v; v.u = ((uint32_t)h) << 16;
  return v.f;
}

__global__ void qjl_prep(const float* __restrict__ S, unsigned short* __restrict__ ST) {
  int i = blockIdx.x * blockDim.x + threadIdx.x;  // grid covers 65536
  const int j = i & 7;
  const int l = (i >> 3) & 63;
  const int c = (i >> 9) & 3;
  const int t = (i >> 11) & 3;
  const int h = (i >> 13) & 1;
  const int s = i >> 14;
  const int m = s * 64 + t * 16 + (l & 15);
  const int k = c * 32 + (l >> 4) * 8 + j;
  const float f = S[m * 128 + k];
  const unsigned short hi = f2bf(f);
  ST[i] = h ? f2bf(f - bf2f(hi)) : hi;
}

__global__ __launch_bounds__(1024, 4) void qjl_main(
    const float* __restrict__ Q, const float* __restrict__ K,
    const unsigned short* __restrict__ ST,
    float* __restrict__ out, unsigned int* __restrict__ blockCount,
    unsigned int* __restrict__ wl) {
  __shared__ unsigned short sST[ST_SHORTS];  // 128 KB
  __shared__ unsigned int l_cnt;
  __shared__ unsigned int l_ent[SEG];

  // ---- stage ST into LDS, coalesced: 8192 int4, 8 per thread ----
  {
    const int4* g = (const int4*)ST;
    int4* s4 = (int4*)sST;
#pragma unroll
    for (int i = 0; i < 8; ++i) s4[threadIdx.x + i * 1024] = g[threadIdx.x + i * 1024];
  }
  if (threadIdx.x == 0) l_cnt = 0u;
  __syncthreads();

  const int wave = threadIdx.x >> 6;
  const int lane = threadIdx.x & 63;
  const int col  = lane & 15;   // data-row within 16-row tile (D col)
  const int kg   = lane >> 4;   // k-group for operand frags
  const int rowbase = blockIdx.x * 512 + wave * 32;  // 32 rows per wave

  // sign masks: bit (s&1)*16 + t*4 + r of smask[a][s>>1]
  unsigned int smask[2][2] = {{0u, 0u}, {0u, 0u}};

  // ================= PASS 1: key projections -> sign bits =================
  {
    bf16x8 khB[2][4], klB[2][4];
#pragma unroll
    for (int a = 0; a < 2; ++a) {
      const float* krow = K + (size_t)(rowbase + a * 16 + col) * 128 + kg * 8;
#pragma unroll
      for (int c = 0; c < 4; ++c) {
        float kf[8];
        *(float4*)(&kf[0]) = *(const float4*)(krow + c * 32);
        *(float4*)(&kf[4]) = *(const float4*)(krow + c * 32 + 4);
#pragma unroll
        for (int j = 0; j < 8; ++j) {
          unsigned short h = f2bf(kf[j]);
          khB[a][c][j] = (short)h;
          klB[a][c][j] = (short)f2bf(kf[j] - bf2f(h));
        }
      }
    }

#pragma unroll
    for (int s = 0; s < 4; ++s) {
      f32x4 acck[2][4];
#pragma unroll
      for (int a = 0; a < 2; ++a)
#pragma unroll
        for (int t = 0; t < 4; ++t) acck[a][t] = (f32x4){0.f, 0.f, 0.f, 0.f};
#pragma unroll
      for (int t = 0; t < 4; ++t) {
#pragma unroll
        for (int c = 0; c < 4; ++c) {
          const bf16x8 bh = *(const bf16x8*)(sST + (((s * 2 + 0) * 4 + t) * 4 + c) * 512 + lane * 8);
          const bf16x8 bl = *(const bf16x8*)(sST + (((s * 2 + 1) * 4 + t) * 4 + c) * 512 + lane * 8);
#pragma unroll
          for (int a = 0; a < 2; ++a) {
            acck[a][t] = __builtin_amdgcn_mfma_f32_16x16x32_bf16(bh, khB[a][c], acck[a][t], 0, 0, 0);
            acck[a][t] = __builtin_amdgcn_mfma_f32_16x16x32_bf16(bh, klB[a][c], acck[a][t], 0, 0, 0);
            acck[a][t] = __builtin_amdgcn_mfma_f32_16x16x32_bf16(bl, khB[a][c], acck[a][t], 0, 0, 0);
          }
        }
      }
      // epilogue: pack signs, push borderline entries
#pragma unroll
      for (int a = 0; a < 2; ++a)
#pragma unroll
        for (int t = 0; t < 4; ++t)
#pragma unroll
          for (int r = 0; r < 4; ++r) {
            const float kp = acck[a][t][r];
            if (kp > 0.f) smask[a][s >> 1] |= (1u << ((s & 1) * 16 + t * 4 + r));
            if (__builtin_fabsf(kp) < DELTA) {
              const int m = s * 64 + t * 16 + kg * 4 + r;
              const int row = rowbase + a * 16 + col;
              const unsigned int code = (kp > 0.f) ? 1u : 2u;  // matches applied sign
              const unsigned int idx = atomicAdd(&l_cnt, 1u);
              if (idx < SEG) l_ent[idx] = (code << 25) | ((unsigned int)row << 8) | (unsigned int)m;
            }
          }
    }
  }

  // ================= PASS 2: query projections -> estimator =================
  float part[2] = {0.f, 0.f};
  {
    bf16x8 qB[2][4];
#pragma unroll
    for (int a = 0; a < 2; ++a) {
      const float* qrow = Q + (size_t)(rowbase + a * 16 + col) * 128 + kg * 8;
#pragma unroll
      for (int c = 0; c < 4; ++c) {
        float qf[8];
        *(float4*)(&qf[0]) = *(const float4*)(qrow + c * 32);
        *(float4*)(&qf[4]) = *(const float4*)(qrow + c * 32 + 4);
#pragma unroll
        for (int j = 0; j < 8; ++j) qB[a][c][j] = (short)f2bf(qf[j]);
      }
    }

#pragma unroll
    for (int s = 0; s < 4; ++s) {
      f32x4 accq[2][4];
#pragma unroll
      for (int a = 0; a < 2; ++a)
#pragma unroll
        for (int t = 0; t < 4; ++t) accq[a][t] = (f32x4){0.f, 0.f, 0.f, 0.f};
#pragma unroll
      for (int t = 0; t < 4; ++t) {
#pragma unroll
        for (int c = 0; c < 4; ++c) {
          const bf16x8 bh = *(const bf16x8*)(sST + (((s * 2 + 0) * 4 + t) * 4 + c) * 512 + lane * 8);
#pragma unroll
          for (int a = 0; a < 2; ++a)
            accq[a][t] = __builtin_amdgcn_mfma_f32_16x16x32_bf16(bh, qB[a][c], accq[a][t], 0, 0, 0);
        }
      }
#pragma unroll
      for (int a = 0; a < 2; ++a)
#pragma unroll
        for (int t = 0; t < 4; ++t)
#pragma unroll
          for (int r = 0; r < 4; ++r) {
            const unsigned int bit = (smask[a][s >> 1] >> ((s & 1) * 16 + t * 4 + r)) & 1u;
            part[a] += bit ? accq[a][t][r] : -accq[a][t][r];
          }
    }
  }

  // reduce the 4 k-groups holding the same data-row (xor lane bits 4,5)
#pragma unroll
  for (int a = 0; a < 2; ++a) {
    float v = part[a];
    v += __shfl_xor(v, 16);
    v += __shfl_xor(v, 32);
    if (lane < 16) out[rowbase + a * 16 + lane] = v * DEQUANT;
  }

  // flush per-block worklist segment
  __syncthreads();
  unsigned int n = l_cnt;
  if (n > SEG) n = SEG;
  if (threadIdx.x == 0) blockCount[blockIdx.x] = n;
  for (unsigned int i = threadIdx.x; i < n; i += 1024)
    wl[(size_t)blockIdx.x * SEG + i] = l_ent[i];
}

__global__ __launch_bounds__(1024) void qjl_fix(
    const float* __restrict__ Q, const float* __restrict__ K, const float* __restrict__ S,
    float* __restrict__ out, const unsigned int* __restrict__ blockCount,
    const unsigned int* __restrict__ wl) {
  const unsigned int n = blockCount[blockIdx.x];
  const int lane = threadIdx.x & 63;
  const int wave = threadIdx.x >> 6;  // 16 waves
  for (unsigned int e = wave; e < n; e += 16) {
    const unsigned int ent = wl[(size_t)blockIdx.x * SEG + e];
    const unsigned int m = ent & 255u;
    const unsigned int row = (ent >> 8) & 0x1FFFFu;
    const unsigned int code = ent >> 25;
    const float s_old = (code == 1u) ? 1.f : -1.f;
    const float* kr = K + (size_t)row * 128;
    const float* qr = Q + (size_t)row * 128;
    const float* sr = S + (size_t)m * 128;
    const int d = lane * 2;
    double kp = (double)kr[d] * (double)sr[d] + (double)kr[d + 1] * (double)sr[d + 1];
    double qp = (double)qr[d] * (double)sr[d] + (double)qr[d + 1] * (double)sr[d + 1];
#pragma unroll
    for (int mask = 1; mask < 64; mask <<= 1) {
      kp += __shfl_xor(kp, mask);
      qp += __shfl_xor(qp, mask);
    }
    if (lane == 0) {
      const float s_new = (kp > 0.0) ? 1.f : ((kp < 0.0) ? -1.f : 0.f);
      const float dlt = (s_new - s_old) * (float)qp * DEQUANT;
      if (dlt != 0.f) atomicAdd(out + row, dlt);
    }
  }
}

extern "C" void kernel_launch(void* const* d_in, const int* in_sizes, int n_in,
                              void* d_out, int out_size, void* d_ws, size_t ws_size,
                              hipStream_t stream) {
  const float* Q = (const float*)d_in[0];
  const float* K = (const float*)d_in[1];
  const float* S = (const float*)d_in[2];
  float* out = (float*)d_out;
  const int rows = in_sizes[0] / 128;  // 4*32768 = 131072
  const int nblk = rows / 512;         // 256 blocks, 512 rows each

  // workspace: [ST bf16 65536][blockCount u32 nblk][wl u32 nblk*SEG]
  unsigned short* ST = (unsigned short*)d_ws;
  unsigned int* blockCount = (unsigned int*)((char*)d_ws + (size_t)ST_SHORTS * 2);
  unsigned int* wl = blockCount + nblk;

  hipLaunchKernelGGL(qjl_prep, dim3(ST_SHORTS / 256), dim3(256), 0, stream, S, ST);
  hipLaunchKernelGGL(qjl_main, dim3(nblk), dim3(1024), 0, stream,
                     Q, K, ST, out, blockCount, wl);
  hipLaunchKernelGGL(qjl_fix, dim3(nblk), dim3(1024), 0, stream,
                     Q, K, S, out, blockCount, wl);
}